// Round 7
// baseline (2057.657 us; speedup 1.0000x reference)
//
#include <hip/hip_runtime.h>
#include <hip/hip_cooperative_groups.h>
#include <math.h>

namespace cg = cooperative_groups;

#define NNODES 20000
#define NROWP  20096   // padded to multiple of 128
#define NEDGES 320000
#define HDIM   256
#define ODIM   128
#define TSTEPS 3
#define KCAT   512     // [msg | h] concatenated K
#define GAT_NB ((NNODES+3)/4)   // 5000
#define RB64   (NROWP/64)       // 314
#define RB128  (NROWP/128)      // 157
#define FGRID  1024             // 4 blocks/CU x 256 CUs (guaranteed by launch_bounds(256,4))

typedef __bf16 bf16x8 __attribute__((ext_vector_type(8)));
typedef __bf16 bf16x4 __attribute__((ext_vector_type(4)));
typedef float  f32x4  __attribute__((ext_vector_type(4)));

#define LOG2E 1.44269504f
__device__ __forceinline__ float fexp2_(float x){ return __builtin_amdgcn_exp2f(x); }
__device__ __forceinline__ float frcp_(float x){ return __builtin_amdgcn_rcpf(x); }
__device__ __forceinline__ float fsig_(float x){ return frcp_(1.f + fexp2_(-LOG2E*x)); }
__device__ __forceinline__ float ftanh_(float x){ float t = fexp2_(2.f*LOG2E*x); return 1.f - 2.f*frcp_(t+1.f); }
__device__ __forceinline__ float felu_(float x){ return (x>0.f)? x : (fexp2_(LOG2E*x)-1.f); }

__device__ __forceinline__ void load_lds16(const void* g, void* l){
  __builtin_amdgcn_global_load_lds((const __attribute__((address_space(1))) void*)g,
                                   (__attribute__((address_space(3))) void*)l, 16, 0, 0);
}

// BK=64 swizzle (8 granules/row): slot = row*8 + (g ^ (row&7))  [0 conflicts measured]
__device__ __forceinline__ bf16x8 lds_frag64(const __bf16* Ls, int rowbase, int lane, int kk){
  int row = rowbase + (lane&15);
  int g = (lane>>4) + (kk<<2);
  int slot = (row<<3) + (g ^ (row&7));
  return *(const bf16x8*)&Ls[slot<<3];
}

// T1 bijective XCD swizzle (m204 variant)
template<int NWG>
__device__ __forceinline__ int xcd_swz(int b){
  constexpr int Q = NWG/8, R = NWG%8;
  int x = b & 7, i = b >> 3;
  if (R == 0) return x*Q + i;
  return (x < R) ? (x*(Q+1) + i) : (R*(Q+1) + (x-R)*Q + i);
}

// ================= phase bodies (shared by fused kernel and fallback wrappers) ==========

// ---- setup: hist(deg) || cvt h->Acat || pack weights || zero as_/ad_ ; domain i<NNODES*64
__device__ __forceinline__ void setup_body(int i,
    const int* __restrict__ dst, int* __restrict__ deg,
    const float* __restrict__ xc, __bf16* __restrict__ Acat,
    const float* __restrict__ Wih, const float* __restrict__ Whh,
    const float* __restrict__ Wg, const float* __restrict__ Lw,
    __bf16* __restrict__ Bf, __bf16* __restrict__ wgb,
    __bf16* __restrict__ lwb, float* __restrict__ asad){
  if (i < NEDGES) atomicAdd(&deg[dst[i]], 1);
  if (i < NNODES*64){
    int row = i>>6, c = (i&63)<<2;
    float4 v = *(const float4*)&xc[(size_t)row*HDIM + c];
    bf16x4 o; o[0]=(__bf16)v.x; o[1]=(__bf16)v.y; o[2]=(__bf16)v.z; o[3]=(__bf16)v.w;
    *(bf16x4*)&Acat[(size_t)row*KCAT + 256 + c] = o;
  }
  if (i < 1024*128){
    int row = i>>7, kc = (i&127)<<2;
    int gate = row>>8, c = row&255;
    float4 v = make_float4(0,0,0,0);
    if (gate==0 || gate==1){
      v = (kc<256) ? *(const float4*)&Wih[(size_t)(gate*256+c)*HDIM + kc]
                   : *(const float4*)&Whh[(size_t)(gate*256+c)*HDIM + kc-256];
    } else if (gate==2){
      if (kc<256) v = *(const float4*)&Wih[(size_t)(512+c)*HDIM + kc];
    } else {
      if (kc>=256) v = *(const float4*)&Whh[(size_t)(512+c)*HDIM + kc-256];
    }
    bf16x4 o; o[0]=(__bf16)v.x; o[1]=(__bf16)v.y; o[2]=(__bf16)v.z; o[3]=(__bf16)v.w;
    *(bf16x4*)&Bf[(size_t)row*KCAT + kc] = o;
  } else if (i < 1024*128 + 256*64){
    int j = i - 1024*128;
    float4 v = ((const float4*)Wg)[j];
    bf16x4 o; o[0]=(__bf16)v.x; o[1]=(__bf16)v.y; o[2]=(__bf16)v.z; o[3]=(__bf16)v.w;
    ((bf16x4*)wgb)[j] = o;
  } else if (i < 1024*128 + 256*64 + 128*64){
    int j = i - 1024*128 - 256*64;
    float4 v = ((const float4*)Lw)[j];
    bf16x4 o; o[0]=(__bf16)v.x; o[1]=(__bf16)v.y; o[2]=(__bf16)v.z; o[3]=(__bf16)v.w;
    ((bf16x4*)lwb)[j] = o;
  }
  if (i < 2*NNODES) asad[i] = 0.f;
}

// ---- exclusive scan over deg, 1 block x 256 thr x 80/thread; writes rowptr AND rowptr2
__device__ __forceinline__ void scan_body(const int* __restrict__ deg, int* __restrict__ rowptr,
                                          int* __restrict__ rowptr2, char* SMEM, int tx){
  const int PER = 80;   // 256*80 = 20480 >= NNODES
  int lane = tx&63, w = tx>>6;
  int base = tx*PER;
  int s = 0;
  #pragma unroll 8
  for (int k=0;k<PER;k++) s += (base+k < NNODES)? deg[base+k] : 0;
  int incl = s;
  #pragma unroll
  for (int off=1; off<64; off<<=1){ int t = __shfl_up(incl, off); if (lane>=off) incl += t; }
  int* wtot = (int*)SMEM;
  if (lane==63) wtot[w] = incl;
  __syncthreads();
  if (w==0 && lane<4){
    int x = wtot[lane];
    #pragma unroll
    for (int off=1; off<4; off<<=1){ int t = __shfl_up(x, off); if (lane>=off) x += t; }
    wtot[lane] = x;
  }
  __syncthreads();
  int wbase = (w>0)? wtot[w-1] : 0;
  int run = wbase + incl - s;
  for (int k=0;k<PER;k++){
    int idx = base+k;
    if (idx < NNODES){
      int d = deg[idx];
      rowptr[idx] = run; rowptr2[idx] = run;
      run += d;
    }
  }
  if (tx==255) rowptr[NNODES] = wbase + incl;
}

// ---- single-buffer BK=64 MFMA GEMM tile (R2-proven at 4 blocks/CU): 64r x 128c, 4 waves
template<int YC, bool F32OUT, bool ALPHA, int NWG>
__device__ __forceinline__ void gemm_tile(int bid, const __bf16* __restrict__ A, int lda,
    const __bf16* __restrict__ B, const float* __restrict__ bias,
    __bf16* __restrict__ Cb, float* __restrict__ Cf, int ldc, int Mreal,
    const float* __restrict__ att_s, const float* __restrict__ att_d,
    float* __restrict__ as_, float* __restrict__ ad_, char* SMEM, int tx){
  __bf16* As = (__bf16*)SMEM;            // 64*64  = 8KB
  __bf16* Bs = (__bf16*)(SMEM + 8192);   // 128*64 = 16KB
  int wgid = xcd_swz<NWG>(bid);
  int r0 = (wgid/YC)*64, c0 = (wgid%YC)*128;
  int lane = tx&63, w = tx>>6;
  int rbase = (w&1)*32, cbase = (w>>1)*64;
  f32x4 acc[2][4] = {};
  for (int k0=0; k0<HDIM; k0+=64){
    #pragma unroll
    for (int q=0;q<2;q++){                 // A: 512 granules
      int idx = q*256 + w*64 + lane;
      int row = idx>>3, kg = (idx&7) ^ (row&7);
      load_lds16(A + (size_t)(r0+row)*lda + k0 + (kg<<3),
                 (char*)As + (q*256 + w*64)*16);
    }
    #pragma unroll
    for (int q=0;q<4;q++){                 // B: 1024 granules
      int idx = q*256 + w*64 + lane;
      int row = idx>>3, kg = (idx&7) ^ (row&7);
      load_lds16(B + (size_t)(c0+row)*HDIM + k0 + (kg<<3),
                 (char*)Bs + (q*256 + w*64)*16);
    }
    __syncthreads();
    #pragma unroll
    for (int kk=0;kk<2;kk++){
      bf16x8 a[2], bb[4];
      #pragma unroll
      for (int i=0;i<2;i++) a[i] = lds_frag64(As, rbase + i*16, lane, kk);
      #pragma unroll
      for (int j=0;j<4;j++) bb[j] = lds_frag64(Bs, cbase + j*16, lane, kk);
      #pragma unroll
      for (int i=0;i<2;i++)
        #pragma unroll
        for (int j=0;j<4;j++)
          acc[i][j] = __builtin_amdgcn_mfma_f32_16x16x32_bf16(a[i], bb[j], acc[i][j], 0,0,0);
    }
    __syncthreads();
  }
  int grb = r0 + rbase, gcb = c0 + cbase;
  #pragma unroll
  for (int i=0;i<2;i++){
    #pragma unroll
    for (int j=0;j<4;j++){
      int gc = gcb + j*16 + (lane&15);
      float bv = F32OUT ? bias[gc] : 0.f;
      #pragma unroll
      for (int r=0;r<4;r++){
        int gr = grb + i*16 + ((lane>>4)<<2) + r;
        if (gr >= Mreal) continue;
        float v = acc[i][j][r] + bv;
        if (F32OUT) Cf[(size_t)gr*ldc + gc] = v;
        else        Cb[(size_t)gr*ldc + gc] = (__bf16)v;
      }
    }
  }
  if (ALPHA){
    float ps[2][4] = {}, pd[2][4] = {};
    #pragma unroll
    for (int j=0;j<4;j++){
      int gc = gcb + j*16 + (lane&15);
      float sv = att_s[gc], dv = att_d[gc];
      #pragma unroll
      for (int i=0;i<2;i++)
        #pragma unroll
        for (int r=0;r<4;r++){
          ps[i][r] += acc[i][j][r]*sv;
          pd[i][r] += acc[i][j][r]*dv;
        }
    }
    #pragma unroll
    for (int m=1;m<16;m<<=1){
      #pragma unroll
      for (int i=0;i<2;i++)
        #pragma unroll
        for (int r=0;r<4;r++){
          ps[i][r] += __shfl_xor(ps[i][r], m);
          pd[i][r] += __shfl_xor(pd[i][r], m);
        }
    }
    if ((lane&15)==0){
      #pragma unroll
      for (int i=0;i<2;i++)
        #pragma unroll
        for (int r=0;r<4;r++){
          int gr = grb + i*16 + ((lane>>4)<<2) + r;
          if (gr < Mreal){
            atomicAdd(&as_[gr], ps[i][r]);
            atomicAdd(&ad_[gr], pd[i][r]);
          }
        }
    }
  }
}

// ---- GAT softmax+aggregate body: 4 nodes/block, 1 wave/node, 32 lanes/row
__device__ __forceinline__ void gat_body(int nb, const __bf16* __restrict__ xpb,
    const float* __restrict__ as_, const float* __restrict__ ad_,
    const int* __restrict__ rowptr, const int* __restrict__ ssrc,
    const float* __restrict__ gat_bias, __bf16* __restrict__ Acat, int tx){
  int node = nb*4 + (tx>>6);
  int lane = tx & 63;
  if (node >= NNODES) return;
  int beg = rowptr[node], end = rowptr[node+1];
  int deg = end - beg;
  float adv = ad_[node];
  int half = lane>>5, col = lane&31;

  float acc[8] = {0,0,0,0,0,0,0,0};

  if (deg <= 64){
    float a = -INFINITY; int sreg = 0;
    if (lane < deg){
      sreg = ssrc[beg+lane];
      a = as_[sreg] + adv;
      a = (a>0.f)? a : 0.01f*a;
    }
    float mx = a;
    #pragma unroll
    for (int off=32; off; off>>=1) mx = fmaxf(mx, __shfl_xor(mx,off));
    float e = (lane<deg)? fexp2_(LOG2E*(a-mx)) : 0.f;
    float sm = e;
    #pragma unroll
    for (int off=32; off; off>>=1) sm += __shfl_xor(sm,off);
    float creg = e*frcp_(fmaxf(sm,1e-16f));

    int j = 0;
    for (; j+16<=deg; j+=16){            // 8 gathers in flight per lane
      float cc[8]; int rr[8]; bf16x8 vv[8];
      #pragma unroll
      for (int k=0;k<8;k++){
        cc[k] = __shfl(creg, j+2*k+half);
        rr[k] = __shfl(sreg, j+2*k+half);
      }
      #pragma unroll
      for (int k=0;k<8;k++) vv[k] = *(const bf16x8*)&xpb[(size_t)rr[k]*HDIM + col*8];
      #pragma unroll
      for (int k=0;k<8;k++)
        #pragma unroll
        for (int t=0;t<8;t++) acc[t] += cc[k]*(float)vv[k][t];
    }
    for (; j+8<=deg; j+=8){              // 4 in flight
      float cc[4]; int rr[4]; bf16x8 vv[4];
      #pragma unroll
      for (int k=0;k<4;k++){
        cc[k] = __shfl(creg, j+2*k+half);
        rr[k] = __shfl(sreg, j+2*k+half);
      }
      #pragma unroll
      for (int k=0;k<4;k++) vv[k] = *(const bf16x8*)&xpb[(size_t)rr[k]*HDIM + col*8];
      #pragma unroll
      for (int k=0;k<4;k++)
        #pragma unroll
        for (int t=0;t<8;t++) acc[t] += cc[k]*(float)vv[k][t];
    }
    for (; j+4<=deg; j+=4){              // 2 in flight
      float c0=__shfl(creg,j+half),  c1=__shfl(creg,j+2+half);
      int   r0=__shfl(sreg,j+half),  r1=__shfl(sreg,j+2+half);
      bf16x8 v0 = *(const bf16x8*)&xpb[(size_t)r0*HDIM + col*8];
      bf16x8 v1 = *(const bf16x8*)&xpb[(size_t)r1*HDIM + col*8];
      #pragma unroll
      for (int t=0;t<8;t++) acc[t] += c0*(float)v0[t] + c1*(float)v1[t];
    }
    for (; j<deg; j+=2){
      int jj = j + half;
      float cf = __shfl(creg, jj);
      int   rw = __shfl(sreg, jj);
      if (jj < deg){
        bf16x8 v = *(const bf16x8*)&xpb[(size_t)rw*HDIM + col*8];
        #pragma unroll
        for (int t=0;t<8;t++) acc[t] += cf*(float)v[t];
      }
    }
  } else {
    float mx = -INFINITY;
    for (int e=beg+lane; e<end; e+=64){
      float a = as_[ssrc[e]] + adv;
      a = (a>0.f)? a : 0.01f*a;
      mx = fmaxf(mx, a);
    }
    #pragma unroll
    for (int off=32; off; off>>=1) mx = fmaxf(mx, __shfl_xor(mx,off));
    float sm = 0.f;
    for (int e=beg+lane; e<end; e+=64){
      float a = as_[ssrc[e]] + adv;
      a = (a>0.f)? a : 0.01f*a;
      sm += fexp2_(LOG2E*(a-mx));
    }
    #pragma unroll
    for (int off=32; off; off>>=1) sm += __shfl_xor(sm,off);
    float rsc = frcp_(fmaxf(sm,1e-16f));
    for (int j=0; j<deg; j+=2){
      int jj = j + half;
      if (jj < deg){
        int rw = ssrc[beg+jj];
        float a = as_[rw] + adv;
        a = (a>0.f)? a : 0.01f*a;
        float cf = fexp2_(LOG2E*(a-mx))*rsc;
        bf16x8 v = *(const bf16x8*)&xpb[(size_t)rw*HDIM + col*8];
        #pragma unroll
        for (int t=0;t<8;t++) acc[t] += cf*(float)v[t];
      }
    }
  }

  #pragma unroll
  for (int t=0;t<8;t++) acc[t] += __shfl_down(acc[t], 32);
  if (half==0){
    float4 b0 = *(const float4*)&gat_bias[col*8];
    float4 b1 = *(const float4*)&gat_bias[col*8+4];
    float bb[8] = {b0.x,b0.y,b0.z,b0.w,b1.x,b1.y,b1.z,b1.w};
    bf16x8 ov;
    #pragma unroll
    for (int t=0;t<8;t++) ov[t] = (__bf16)felu_(acc[t]+bb[t]);
    *(bf16x8*)&Acat[(size_t)node*KCAT + col*8] = ov;   // msg slot
  }
}

// ---- GRU tile (R5-proven): single-buffer 28KB, 128r x 32c, 3 effective gates
__device__ __forceinline__ void gru_tile(int b, const __bf16* __restrict__ Acat,
    __bf16* __restrict__ AcatN, const __bf16* __restrict__ Bf,
    const float* __restrict__ bih, const float* __restrict__ bhh,
    float* __restrict__ as_, float* __restrict__ ad_, char* SMEM, int tx){
  __bf16* As = (__bf16*)SMEM;             // 128*64 = 16KB
  __bf16* Bs = (__bf16*)(SMEM + 16384);   // 96*64  = 12KB
  int wgid = xcd_swz<RB128*8>(b);
  int r0 = (wgid>>3)*128, c0 = (wgid&7)*32;
  int lane = tx&63, w = tx>>6;
  int rbase = w*32;
  f32x4 acc[4][2][2] = {};   // acc[2]=xn(K<256), acc[3]=hn(K>=256)

  #pragma unroll
  for (int t=0; t<KCAT/64; t++){
    int k0 = t*64, tg = (t<4)?2:3;
    #pragma unroll
    for (int q=0;q<4;q++){
      int idx = q*256 + w*64 + lane;
      int row = idx>>3, kg = (idx&7) ^ (row&7);
      load_lds16(Acat + (size_t)(r0+row)*KCAT + k0 + (kg<<3),
                 (char*)As + (q*256 + w*64)*16);
    }
    #pragma unroll
    for (int q=0;q<3;q++){
      int idx = q*256 + w*64 + lane;
      int row = idx>>3, kg = (idx&7) ^ (row&7);
      int gsel = row>>5;
      int grow = (gsel==2 ? tg : gsel)*256 + c0 + (row&31);
      load_lds16(Bf + (size_t)grow*KCAT + k0 + (kg<<3),
                 (char*)Bs + (q*256 + w*64)*16);
    }
    __syncthreads();
    #pragma unroll
    for (int kk=0;kk<2;kk++){
      bf16x8 a[2], b0[2], b1[2], bt[2];
      #pragma unroll
      for (int i=0;i<2;i++) a[i] = lds_frag64(As, rbase + i*16, lane, kk);
      #pragma unroll
      for (int j=0;j<2;j++){
        b0[j] = lds_frag64(Bs, 0  + j*16, lane, kk);
        b1[j] = lds_frag64(Bs, 32 + j*16, lane, kk);
        bt[j] = lds_frag64(Bs, 64 + j*16, lane, kk);
      }
      #pragma unroll
      for (int i=0;i<2;i++)
        #pragma unroll
        for (int j=0;j<2;j++){
          acc[0][i][j] = __builtin_amdgcn_mfma_f32_16x16x32_bf16(a[i], b0[j], acc[0][i][j], 0,0,0);
          acc[1][i][j] = __builtin_amdgcn_mfma_f32_16x16x32_bf16(a[i], b1[j], acc[1][i][j], 0,0,0);
          if (t < 4)
            acc[2][i][j] = __builtin_amdgcn_mfma_f32_16x16x32_bf16(a[i], bt[j], acc[2][i][j], 0,0,0);
          else
            acc[3][i][j] = __builtin_amdgcn_mfma_f32_16x16x32_bf16(a[i], bt[j], acc[3][i][j], 0,0,0);
        }
    }
    __syncthreads();
  }
  int grb = r0 + rbase;
  #pragma unroll
  for (int i=0;i<2;i++){
    #pragma unroll
    for (int j=0;j<2;j++){
      int gc = c0 + j*16 + (lane&15);
      float br_ = bih[gc]     + bhh[gc];
      float bz_ = bih[256+gc] + bhh[256+gc];
      float bnx = bih[512+gc];
      float bnh = bhh[512+gc];
      #pragma unroll
      for (int r=0;r<4;r++){
        int gr = grb + i*16 + ((lane>>4)<<2) + r;
        if (gr >= NNODES) continue;
        float hold = (float)Acat[(size_t)gr*KCAT + 256 + gc];
        float rr = fsig_(acc[0][i][j][r] + br_);
        float zz = fsig_(acc[1][i][j][r] + bz_);
        float nn = ftanh_(acc[2][i][j][r] + bnx + rr*(acc[3][i][j][r] + bnh));
        AcatN[(size_t)gr*KCAT + 256 + gc] = (__bf16)((1.f-zz)*nn + zz*hold);
      }
    }
  }
  // zero as_/ad_ for the next timestep's fused-alpha atomics
  if ((wgid&7)==0 && (lane&15)==0){
    #pragma unroll
    for (int i=0;i<2;i++)
      #pragma unroll
      for (int r=0;r<4;r++){
        int gr = grb + i*16 + ((lane>>4)<<2) + r;
        if (gr < NNODES){ as_[gr] = 0.f; ad_[gr] = 0.f; }
      }
  }
}

// ================= fused cooperative kernel: the ENTIRE pipeline, 1 launch =================
struct FArgs {
  const float *xc, *Wg, *att_s, *att_d, *gat_b, *Wih, *Whh, *bih, *bhh, *Lw, *lin_b;
  const int *src, *dst;
  float *out;
  __bf16 *AcA, *AcB, *xpb, *Bf, *wgb, *lwb;
  float *as_, *ad_;
  int *deg, *rowptr, *rowptr2, *ssrc;
};

__global__ __launch_bounds__(256,4)
void fused_all(FArgs P){
  cg::grid_group grid = cg::this_grid();
  __shared__ __align__(16) char SMEM[28672];   // union: gemm 24KB / gru 28KB / scan 16B
  int tx = threadIdx.x;
  int gtid = blockIdx.x*256 + tx;
  const int GSTR = FGRID*256;

  // Z: zero deg
  for (int i=gtid; i<NNODES; i+=GSTR) P.deg[i] = 0;
  grid.sync();
  // H: histogram + cvt h + weight packing + zero as_/ad_
  for (int i=gtid; i<NNODES*64; i+=GSTR)
    setup_body(i, P.dst, P.deg, P.xc, P.AcA, P.Wih, P.Whh, P.Wg, P.Lw, P.Bf, P.wgb, P.lwb, P.as_);
  grid.sync();
  // SCAN (block 0 only)
  if (blockIdx.x==0) scan_body(P.deg, P.rowptr, P.rowptr2, SMEM, tx);
  grid.sync();
  // SCATTER (rowptr2 doubles as fill counter)
  for (int e=gtid; e<NEDGES; e+=GSTR){
    int d = P.dst[e];
    int pos = atomicAdd(&P.rowptr2[d], 1);
    P.ssrc[pos] = P.src[e];
  }
  grid.sync();

  __bf16 *Ac = P.AcA, *An = P.AcB;
  for (int t=0; t<TSTEPS; t++){
    for (int tb=blockIdx.x; tb<RB64*2; tb+=FGRID)
      gemm_tile<2,false,true,RB64*2>(tb, Ac+256, KCAT, P.wgb, nullptr, P.xpb, nullptr,
                                     HDIM, NNODES, P.att_s, P.att_d, P.as_, P.ad_, SMEM, tx);
    grid.sync();
    for (int nb=blockIdx.x; nb<GAT_NB; nb+=FGRID)
      gat_body(nb, P.xpb, P.as_, P.ad_, P.rowptr, P.ssrc, P.gat_b, Ac, tx);
    grid.sync();
    for (int tb=blockIdx.x; tb<RB128*8; tb+=FGRID)
      gru_tile(tb, Ac, An, P.Bf, P.bih, P.bhh, P.as_, P.ad_, SMEM, tx);
    grid.sync();
    __bf16* tmp = Ac; Ac = An; An = tmp;
  }
  for (int tb=blockIdx.x; tb<RB64; tb+=FGRID)
    gemm_tile<1,true,false,RB64>(tb, Ac+256, KCAT, P.lwb, P.lin_b, nullptr, P.out,
                                 ODIM, NNODES, nullptr, nullptr, nullptr, nullptr, SMEM, tx);
}

// ================= fallback wrappers (R5 multi-launch path) =================
__global__ void setup1_k(FArgs P){
  int i = blockIdx.x*blockDim.x + threadIdx.x;
  setup_body(i, P.dst, P.deg, P.xc, P.AcA, P.Wih, P.Whh, P.Wg, P.Lw, P.Bf, P.wgb, P.lwb, P.as_);
}
__global__ void scan_k(FArgs P){
  __shared__ __align__(16) char SM[64];
  scan_body(P.deg, P.rowptr, P.rowptr2, SM, threadIdx.x);
}
__global__ void scatter_k(FArgs P){
  int e = blockIdx.x*blockDim.x + threadIdx.x;
  if (e < NEDGES){
    int d = P.dst[e];
    int pos = atomicAdd(&P.rowptr2[d], 1);
    P.ssrc[pos] = P.src[e];
  }
}
template<int YC, bool F32OUT, bool ALPHA, int NWG>
__global__ __launch_bounds__(256,4) void gemm_k(FArgs P, const __bf16* A, const __bf16* B,
    const float* bias, __bf16* Cb, float* Cf, int ldc){
  __shared__ __align__(16) char SM[24576];
  gemm_tile<YC,F32OUT,ALPHA,NWG>(blockIdx.x, A, KCAT, B, bias, Cb, Cf, ldc, NNODES,
                                 P.att_s, P.att_d, P.as_, P.ad_, SM, threadIdx.x);
}
__global__ __launch_bounds__(256,4) void gat_k(FArgs P, const __bf16* Ac){
  gat_body(blockIdx.x, P.xpb, P.as_, P.ad_, P.rowptr, P.ssrc, P.gat_b, (__bf16*)Ac, threadIdx.x);
}
__global__ __launch_bounds__(256,4) void gru_k(FArgs P, const __bf16* Ac, __bf16* An){
  __shared__ __align__(16) char SM[28672];
  gru_tile(blockIdx.x, Ac, An, P.Bf, P.bih, P.bhh, P.as_, P.ad_, SM, threadIdx.x);
}

// ================= launch =================
extern "C" void kernel_launch(void* const* d_in, const int* in_sizes, int n_in,
                              void* d_out, int out_size, void* d_ws, size_t ws_size,
                              hipStream_t stream) {
  const int* eidx = (const int*)d_in[14];

  const size_t ACAT = (size_t)NROWP*KCAT;
  __bf16* AcA  = (__bf16*)d_ws;
  __bf16* AcB  = AcA + ACAT;
  __bf16* xpb  = AcB + ACAT;                        // [NROWP][256]
  __bf16* Bf   = xpb + (size_t)NROWP*HDIM;          // [1024][512]
  __bf16* wgb  = Bf  + (size_t)1024*KCAT;           // [256][256]
  __bf16* lwb  = wgb + (size_t)HDIM*HDIM;           // [128][256]
  float* as_   = (float*)(lwb + (size_t)ODIM*HDIM);
  float* ad_   = as_ + NNODES;
  int* deg     = (int*)(ad_ + NNODES);
  int* rowptr  = deg + NNODES;
  int* rowptr2 = rowptr + (NNODES+1);
  int* ssrc    = rowptr2 + NNODES;

  FArgs fa;
  fa.xc    = (const float*)d_in[0];
  fa.Wg    = (const float*)d_in[1];
  fa.att_s = (const float*)d_in[2];
  fa.att_d = (const float*)d_in[3];
  fa.gat_b = (const float*)d_in[4];
  fa.Wih   = (const float*)d_in[5];
  fa.Whh   = (const float*)d_in[6];
  fa.bih   = (const float*)d_in[7];
  fa.bhh   = (const float*)d_in[8];
  fa.Lw    = (const float*)d_in[9];
  fa.lin_b = (const float*)d_in[10];
  fa.src   = eidx;
  fa.dst   = eidx + NEDGES;
  fa.out   = (float*)d_out;
  fa.AcA = AcA; fa.AcB = AcB; fa.xpb = xpb; fa.Bf = Bf; fa.wgb = wgb; fa.lwb = lwb;
  fa.as_ = as_; fa.ad_ = ad_;
  fa.deg = deg; fa.rowptr = rowptr; fa.rowptr2 = rowptr2; fa.ssrc = ssrc;

  void* params[] = { &fa };
  hipError_t rc = hipLaunchCooperativeKernel((void*)fused_all, dim3(FGRID), dim3(256),
                                             params, 0, stream);
  if (rc != hipSuccess){
    // fallback: R5-equivalent multi-launch path
    hipMemsetAsync(deg, 0, NNODES*sizeof(int), stream);
    setup1_k<<<NNODES*64/256, 256, 0, stream>>>(fa);
    scan_k<<<1, 256, 0, stream>>>(fa);
    scatter_k<<<(NEDGES+255)/256, 256, 0, stream>>>(fa);
    __bf16* Ac = AcA;
    __bf16* An = AcB;
    for (int t=0; t<TSTEPS; t++){
      gemm_k<2,false,true,RB64*2><<<RB64*2, 256, 0, stream>>>(
          fa, Ac + 256, wgb, nullptr, xpb, nullptr, HDIM);
      gat_k<<<GAT_NB, 256, 0, stream>>>(fa, Ac);
      gru_k<<<RB128*8, 256, 0, stream>>>(fa, Ac, An);
      __bf16* tmp = Ac; Ac = An; An = tmp;
    }
    gemm_k<1,true,false,RB64><<<RB64, 256, 0, stream>>>(
        fa, Ac + 256, lwb, fa.lin_b, nullptr, fa.out, ODIM);
  }
}